// Round 9
// baseline (158634.009 us; speedup 1.0000x reference)
//
#include <hip/hip_runtime.h>

#define BDIM 64
#define TDIM 1024
#define DDIM 256
#define HDIM 512
#define RING 8

typedef unsigned short ushort_t;
typedef unsigned int uint32;
typedef unsigned long long ull;
typedef __attribute__((ext_vector_type(8))) short short8;
typedef __attribute__((ext_vector_type(4))) float f32x4;

__device__ __forceinline__ ushort_t f2bf(float f) {
  union { float f; uint32 u; } v; v.f = f;
  uint32 u = v.u;
  return (ushort_t)((u + 0x7fffu + ((u >> 16) & 1u)) >> 16);
}

__device__ __forceinline__ short8 pack8(float4 a, float4 b) {
  short8 s;
  s[0] = (short)f2bf(a.x); s[1] = (short)f2bf(a.y);
  s[2] = (short)f2bf(a.z); s[3] = (short)f2bf(a.w);
  s[4] = (short)f2bf(b.x); s[5] = (short)f2bf(b.y);
  s[6] = (short)f2bf(b.z); s[7] = (short)f2bf(b.w);
  return s;
}

__device__ __forceinline__ ull pack4bf(f32x4 v) {
  return (ull)f2bf(v[0]) | ((ull)f2bf(v[1]) << 16)
       | ((ull)f2bf(v[2]) << 32) | ((ull)f2bf(v[3]) << 48);
}

__device__ __forceinline__ float sigm(float x) { return 1.0f / (1.0f + __expf(-x)); }
__device__ __forceinline__ float tanh_fast(float x) { return 1.0f - 2.0f / (__expf(2.0f * x) + 1.0f); }

__device__ __forceinline__ uint32 ld_sc1(uint32* p) {
  return __hip_atomic_load(p, __ATOMIC_RELAXED, __HIP_MEMORY_SCOPE_AGENT);
}
__device__ __forceinline__ void st_sc1(uint32* p, uint32 v) {
  __hip_atomic_store(p, v, __ATOMIC_RELAXED, __HIP_MEMORY_SCOPE_AGENT);
}
__device__ __forceinline__ void st_sc1_u64(ull* p, ull v) {
  __hip_atomic_store(p, v, __ATOMIC_RELAXED, __HIP_MEMORY_SCOPE_AGENT);
}
__device__ __forceinline__ ull ld_sc1_u64(const ull* p) {
  return __hip_atomic_load((ull*)p, __ATOMIC_RELAXED, __HIP_MEMORY_SCOPE_AGENT);
}

// L1-invalidate (vector cache only) — the gfx94x workgroup-acquire cache op.
__device__ __forceinline__ void l1_inv() {
  asm volatile("buffer_inv sc0\n\ts_waitcnt vmcnt(0)" ::: "memory");
}

__device__ __forceinline__ void wave_poll_sc1(uint32* fl, uint32 tgt) {
  int it = 0;
  for (;;) {
    uint32 v = ld_sc1(fl);
    if (__all((int)(v >= tgt))) break;
    __builtin_amdgcn_s_sleep(1);
    if (++it > 60000) break;   // bounded: wrong beats hang
  }
  asm volatile("" ::: "memory");
}
// fast poll: L1-inv + plain load (hits XCD-shared L2)
__device__ __forceinline__ void wave_poll_fast(const uint32* fl, uint32 tgt) {
  int it = 0;
  for (;;) {
    l1_inv();
    uint32 v = *(const volatile uint32*)fl;
    if (__all((int)(v >= tgt))) break;
    if (++it > 60000) break;
  }
  asm volatile("" ::: "memory");
}

__device__ __forceinline__ void ds_stage(ushort_t* dst, int tid, const ull* v) {
#pragma unroll
  for (int q = 0; q < 8; ++q) {
    int idx = q * 256 + tid;
    int r = idx >> 7, inner = idx & 127;
    *(ull*)&dst[(r * 512 + inner * 4) ^ ((r & 7) << 3)] = v[q];
  }
}

__device__ __forceinline__ void load_sc1_8(const ull* src, int tid, ull* v) {
#pragma unroll
  for (int q = 0; q < 8; ++q) v[q] = ld_sc1_u64(src + q * 256 + tid);
}
__device__ __forceinline__ void load_fast_8(const ull* src, int tid, ull* v) {
  l1_inv();
#pragma unroll
  for (int q = 0; q < 8; ++q) v[q] = *(const volatile ull*)(src + q * 256 + tid);
}

// ============================ MAIN (r4 verbatim) ============================
__global__ void __launch_bounds__(256, 1)
lstm_fused(const float* __restrict__ x,
           const float* __restrict__ w_ih0, const float* __restrict__ w_hh0,
           const float* __restrict__ b0,
           const float* __restrict__ w_ih1, const float* __restrict__ w_hh1,
           const float* __restrict__ b1,
           float* __restrict__ out,
           uint32* cnt0F, uint32* cnt1F, uint32* consF,
           uint32* h0locF, uint32* h1locF, uint32* voteWs, uint32* probe,
           ushort_t* ring, ushort_t* h1buf, ushort_t* h0loc, ushort_t* h1loc)
{
  const int b     = (int)blockIdx.x;
  const int g     = b & 7;
  const int layer = g >> 2;
  const int bt    = g & 3;
  const int ct    = b >> 3;
  const int tid   = (int)threadIdx.x;
  const int wv    = tid >> 6;
  const int lane  = tid & 63;
  const int lr    = lane & 15;
  const int lg    = lane >> 4;

  __shared__ __align__(16) ushort_t Is[16 * 512];
  __shared__ __align__(16) ushort_t Hs[16 * 512];
  __shared__ float gates[4][16][16];
  __shared__ int fastLds;

  uint32* grpXcdMask = voteWs;
  uint32* grpRep     = voteWs + 8;
  uint32* grpBad     = voteWs + 16;
  uint32* arrCnt     = voteWs + 24;
  uint32* xcdAll     = voteWs + 25;

  if (tid == 0) {
    uint32 xcd;
    asm volatile("s_getreg_b32 %0, hwreg(HW_REG_XCC_ID, 0, 4)" : "=s"(xcd));
    xcd &= 15u;
    *(volatile uint32*)(probe + g * 32 + ct) = 0xA5000000u | (uint32)b;
    asm volatile("s_waitcnt vmcnt(0)" ::: "memory");
    __hip_atomic_fetch_or(grpXcdMask + g, 1u << (xcd & 31u), __ATOMIC_RELAXED, __HIP_MEMORY_SCOPE_AGENT);
    __hip_atomic_fetch_or(xcdAll, 1u << (xcd & 31u), __ATOMIC_RELAXED, __HIP_MEMORY_SCOPE_AGENT);
    __hip_atomic_fetch_add(arrCnt, 1u, __ATOMIC_RELAXED, __HIP_MEMORY_SCOPE_AGENT);
    int it = 0;
    while (ld_sc1(arrCnt) < 256u) { __builtin_amdgcn_s_sleep(8); if (++it > 5000000) break; }
  }
  __syncthreads();

  int probeOk = 1;
  if (wv == 0) {
    int seen = (lane < 32) ? 0 : 1;
    const uint32 expect = 0xA5000000u | (uint32)((lane & 31) * 8 + g);
    for (int it = 0; it < 4000 && !seen; ++it) {
      l1_inv();
      uint32 v = *(volatile uint32*)(probe + g * 32 + (lane & 31));
      if (v == expect) seen = 1;
    }
    probeOk = __all(seen);
  }
  if (tid == 0) {
    if (!probeOk) __hip_atomic_fetch_or(grpBad + g, 1u, __ATOMIC_RELAXED, __HIP_MEMORY_SCOPE_AGENT);
    __hip_atomic_fetch_add(grpRep + g, 1u, __ATOMIC_RELAXED, __HIP_MEMORY_SCOPE_AGENT);
    int it = 0;
    while (ld_sc1(grpRep + g) < 32u) { __builtin_amdgcn_s_sleep(8); if (++it > 5000000) break; }
    uint32 bad = ld_sc1(grpBad + g);
    uint32 gm  = ld_sc1(grpXcdMask + g);
    uint32 am  = ld_sc1(xcdAll);
    fastLds = (bad == 0u && __popc(gm) == 1 && __popc(am) >= 2) ? 1 : 0;
  }

  const int NI  = layer ? 16 : 8;
  const int Din = layer ? HDIM : DDIM;
  const float* wih = layer ? w_ih1 : w_ih0;
  const float* whh = layer ? w_hh1 : w_hh0;
  const float* bb  = layer ? b1 : b0;
  const int grow = wv * HDIM + ct * 16 + lr;

  short8 wf[32];
#pragma unroll
  for (int kf = 0; kf < 32; ++kf) wf[kf] = (short8)((short)0);
#pragma unroll
  for (int kf = 0; kf < 32; ++kf) {
    if (kf < NI + 16) {
      const float* src;
      if (kf < NI) src = wih + (size_t)grow * Din + (size_t)kf * 32 + lg * 8;
      else         src = whh + (size_t)grow * HDIM + (size_t)(kf - NI) * 32 + lg * 8;
      float4 a = *(const float4*)(src);
      float4 bq = *(const float4*)(src + 4);
      wf[kf] = pack8(a, bq);
    }
  }
  const float bias = bb[grow];

  __syncthreads();
  const bool fast = (bool)fastLds;

  const ull* ring_u  = (const ull*)ring;
  const ull* h1buf_u = (const ull*)h1buf;
  const ull* h0loc_u = (const ull*)h0loc;
  const ull* h1loc_u = (const ull*)h1loc;

  float c4[4] = {0.f, 0.f, 0.f, 0.f};
  float4 xp0, xp1, xp2, xp3;
  const int xr = tid >> 4, xc = (tid & 15) * 16, xsw = (xr & 7) << 3;

  if (layer == 0) {
    const float4* xv = (const float4*)(x + (size_t)(bt * 16 + xr) * (TDIM * DDIM) + xc);
    xp0 = xv[0]; xp1 = xv[1]; xp2 = xv[2]; xp3 = xv[3];
  }

  for (int t = 0; t < TDIM; ++t) {
    if (layer == 0) {
      if (wv == 0) {
        if (fast) {
          if (t > 0) {
            asm volatile("s_waitcnt vmcnt(0)" ::: "memory");
            if (lane == 0) st_sc1(cnt0F + bt * 32 + ct, (uint32)t);
          }
          if (t > 0) wave_poll_fast(h0locF + bt * 32 + (lane & 31), (uint32)t);
        } else {
          if (t > 0) wave_poll_sc1(cnt0F + bt * 32 + (lane & 31), (uint32)t);
        }
      } else if (wv == 1) {
        if (t >= RING) wave_poll_sc1(consF + bt * 32 + (lane & 31), (uint32)(t - RING + 1));
      }
    } else {
      if (wv == 0) {
        if (t > 0) {
          if (fast) wave_poll_fast(h1locF + bt * 32 + (lane & 31), (uint32)t);
          else      wave_poll_sc1(cnt1F + bt * 32 + (lane & 31), (uint32)t);
        }
      } else if (wv == 1) {
        wave_poll_sc1(cnt0F + bt * 32 + (lane & 31), (uint32)(t + 1));
      }
    }
    __syncthreads();

    if (layer == 0) {
      *(short8*)&Is[(xr * 512 + xc) ^ xsw]     = pack8(xp0, xp1);
      *(short8*)&Is[(xr * 512 + xc + 8) ^ xsw] = pack8(xp2, xp3);
      if (t > 0) {
        ull hv[8];
        if (fast) load_fast_8(h0loc_u + (size_t)bt * 4096 + (size_t)((t - 1) & 1) * 2048, tid, hv);
        else      load_sc1_8(ring_u + (size_t)((t - 1) & (RING - 1)) * 8192 + (size_t)bt * 2048, tid, hv);
        ds_stage(Hs, tid, hv);
      }
    } else {
      ull rv[8], hv[8];
      load_sc1_8(ring_u + (size_t)(t & (RING - 1)) * 8192 + (size_t)bt * 2048, tid, rv);
      if (t > 0) {
        if (fast) load_fast_8(h1loc_u + (size_t)bt * 4096 + (size_t)((t - 1) & 1) * 2048, tid, hv);
        else      load_sc1_8(h1buf_u + (size_t)((t - 1) & 1) * 8192 + (size_t)bt * 2048, tid, hv);
      }
      ds_stage(Is, tid, rv);
      if (t > 0) ds_stage(Hs, tid, hv);
    }
    __syncthreads();
    if (layer == 1 && tid == 0)
      st_sc1(consF + bt * 32 + ct, (uint32)(t + 1));

    f32x4 acc0 = {0.f, 0.f, 0.f, 0.f}, acc1 = {0.f, 0.f, 0.f, 0.f};
    const int fb  = lr * 512 + lg * 8;
    const int fsw = (lr & 7) << 3;
#pragma unroll
    for (int kf = 0; kf < 16; ++kf) {
      if (kf < NI) {
        const short8 af = *(const short8*)&Is[(fb + kf * 32) ^ fsw];
        if (kf & 1) acc1 = __builtin_amdgcn_mfma_f32_16x16x32_bf16(af, wf[kf], acc1, 0, 0, 0);
        else        acc0 = __builtin_amdgcn_mfma_f32_16x16x32_bf16(af, wf[kf], acc0, 0, 0, 0);
      }
    }
    if (t > 0) {
#pragma unroll
      for (int kf = 0; kf < 16; ++kf) {
        const short8 af = *(const short8*)&Hs[(fb + kf * 32) ^ fsw];
        if (kf & 1) acc1 = __builtin_amdgcn_mfma_f32_16x16x32_bf16(af, wf[NI + kf], acc1, 0, 0, 0);
        else        acc0 = __builtin_amdgcn_mfma_f32_16x16x32_bf16(af, wf[NI + kf], acc0, 0, 0, 0);
      }
    }
#pragma unroll
    for (int i = 0; i < 4; ++i) {
      float v = acc0[i] + acc1[i] + bias;
      float a = (wv < 3) ? sigm(v) : tanh_fast(v);
      gates[wv][lg * 4 + i][lr] = a;
    }
    __syncthreads();

    if (layer == 0 && wv != 0 && t + 1 < TDIM) {
      const float4* xv = (const float4*)(x + (size_t)(bt * 16 + xr) * (TDIM * DDIM)
                                           + (size_t)(t + 1) * DDIM + xc);
      xp0 = xv[0]; xp1 = xv[1]; xp2 = xv[2]; xp3 = xv[3];
    }
    if (wv == 0) {
      const int r  = lane >> 2;
      const int cg = lane & 3;
      f32x4 gi = *(const f32x4*)&gates[0][r][cg * 4];
      f32x4 gf = *(const f32x4*)&gates[1][r][cg * 4];
      f32x4 go = *(const f32x4*)&gates[2][r][cg * 4];
      f32x4 gg = *(const f32x4*)&gates[3][r][cg * 4];
      f32x4 nh4, nc4;
#pragma unroll
      for (int k = 0; k < 4; ++k) {
        float nc = gf[k] * c4[k] + gi[k] * gg[k];
        float nh = go[k] * tanh_fast(nc);
        nc = fminf(fmaxf(nc, -50.f), 50.f);
        nh = fminf(fmaxf(nh, -50.f), 50.f);
        c4[k] = nc; nh4[k] = nh; nc4[k] = nc;
      }
      const ull hv = pack4bf(nh4);
      if (fast) {
        ull* dst = (ull*)((layer == 0 ? h0loc_u : h1loc_u)
                          + (size_t)bt * 4096 + (size_t)(t & 1) * 2048 + r * 128 + ct * 4 + cg);
        *dst = hv;
        asm volatile("s_waitcnt vmcnt(0)" ::: "memory");
        if (lane == 0)
          *(volatile uint32*)((layer == 0 ? h0locF : h1locF) + bt * 32 + ct) = (uint32)(t + 1);
        if (layer == 0) {
          st_sc1_u64((ull*)(ring_u + (size_t)(t & (RING - 1)) * 8192
                            + (size_t)(bt * 16 + r) * 128 + ct * 4 + cg), hv);
        }
      } else {
        ull* dst;
        if (layer == 0)
          dst = (ull*)(ring_u + (size_t)(t & (RING - 1)) * 8192
                       + (size_t)(bt * 16 + r) * 128 + ct * 4 + cg);
        else
          dst = (ull*)(h1buf_u + (size_t)(t & 1) * 8192
                       + (size_t)(bt * 16 + r) * 128 + ct * 4 + cg);
        st_sc1_u64(dst, hv);
        asm volatile("s_waitcnt vmcnt(0)" ::: "memory");
        if (lane == 0) st_sc1((layer == 0 ? cnt0F : cnt1F) + bt * 32 + ct, (uint32)(t + 1));
      }
      if (layer == 1)
        *(f32x4*)&out[(size_t)(bt * 16 + r) * (TDIM * HDIM) + (size_t)t * HDIM + ct * 16 + cg * 4] = nh4;
      if (t == TDIM - 1) {
        const size_t OH = (size_t)BDIM * TDIM * HDIM;
        const size_t OC = OH + 2 * (size_t)BDIM * HDIM;
        *(f32x4*)&out[OH + (size_t)layer * BDIM * HDIM + (size_t)(bt * 16 + r) * HDIM + ct * 16 + cg * 4] = nh4;
        *(f32x4*)&out[OC + (size_t)layer * BDIM * HDIM + (size_t)(bt * 16 + r) * HDIM + ct * 16 + cg * 4] = nc4;
      }
      if (layer == 0 && t + 1 < TDIM) {
        const float4* xv = (const float4*)(x + (size_t)(bt * 16 + xr) * (TDIM * DDIM)
                                             + (size_t)(t + 1) * DDIM + xc);
        xp0 = xv[0]; xp1 = xv[1]; xp2 = xv[2]; xp3 = xv[3];
      }
    }
  }

  if (fast && layer == 0 && wv == 0) {
    asm volatile("s_waitcnt vmcnt(0)" ::: "memory");
    if (lane == 0) st_sc1(cnt0F + bt * 32 + ct, (uint32)TDIM);
  }
}

// ============================ PROBES ============================
// A: pure 16-block sc1 flag-barrier chain. wg=64 fingerprint.
__global__ void __launch_bounds__(64, 1)
probeA(uint32* flags, int iters, int cap) {
  const int b = (int)blockIdx.x;
  if (b & 7) return;
  const int ct = b >> 3;
  const int lane = (int)threadIdx.x & 63;
  for (int k = 1; k <= iters; ++k) {
    if (lane == 0) st_sc1(flags + ct, (uint32)k);
    int it = 0;
    for (;;) {
      uint32 v = ld_sc1(flags + (lane & 15));
      if (__all((int)(v >= (uint32)k))) break;
      if (++it > cap) break;
    }
    asm volatile("" ::: "memory");
  }
}

// B: sc1 data round trip: 512B store + vmcnt + flag + join + 8KB load. wg=128.
__global__ void __launch_bounds__(128, 1)
probeB(uint32* flags, ull* buf, ull* sink, int iters, int cap) {
  const int b = (int)blockIdx.x;
  if (b & 7) return;
  const int ct = b >> 3;
  const int tid = (int)threadIdx.x;
  const int lane = tid & 63;
  ull acc = 0;
  for (int k = 1; k <= iters; ++k) {
    ull* slot = buf + (size_t)(k & 1) * 1024;
    if (tid < 64) st_sc1_u64(slot + ct * 64 + tid, (ull)(k + tid));
    asm volatile("s_waitcnt vmcnt(0)" ::: "memory");
    if (tid == 0) st_sc1(flags + ct, (uint32)k);
    int it = 0;
    for (;;) {
      uint32 v = ld_sc1(flags + (lane & 15));
      if (__all((int)(v >= (uint32)k))) break;
      if (++it > cap) break;
    }
    asm volatile("" ::: "memory");
#pragma unroll
    for (int q = 0; q < 8; ++q) acc += ld_sc1_u64(slot + q * 128 + tid);
  }
  if (tid == 0) sink[ct] = acc;
}

// C: fast-mechanism round trip: plain store + vmcnt + plain flag + inv-poll + plain load. wg=192.
__global__ void __launch_bounds__(192, 1)
probeC(uint32* flags, ull* buf, ull* sink, int iters, int cap) {
  const int b = (int)blockIdx.x;
  if (b & 7) return;
  const int ct = b >> 3;
  const int tid = (int)threadIdx.x;
  const int lane = tid & 63;
  ull acc = 0;
  for (int k = 1; k <= iters; ++k) {
    ull* slot = buf + (size_t)(k & 1) * 1024;
    if (tid < 64) *(volatile ull*)(slot + ct * 64 + tid) = (ull)(k + tid);
    asm volatile("s_waitcnt vmcnt(0)" ::: "memory");
    if (tid == 0) *(volatile uint32*)(flags + ct) = (uint32)k;
    int it = 0;
    for (;;) {
      asm volatile("buffer_inv sc0\n\ts_waitcnt vmcnt(0)" ::: "memory");
      uint32 v = *(volatile uint32*)(flags + (lane & 15));
      if (__all((int)(v >= (uint32)k))) break;
      if (++it > cap) break;
    }
    asm volatile("s_waitcnt vmcnt(0)" ::: "memory");
    if (tid < 128) {
#pragma unroll
      for (int q = 0; q < 8; ++q) acc += *(volatile ull*)(slot + q * 128 + tid);
    }
  }
  if (tid == 0) sink[ct] = acc;
}

// D: single-block r4 compute skeleton (stage + 24 MFMA + gates + pointwise + local
// publish, 3 barriers), no cross-block sync. wg=448 (waves 4-6 barrier-only).
__global__ void __launch_bounds__(448, 1)
probeD(ull* sink, uint32* flagsink, int iters) {
  if (blockIdx.x != 0) return;
  const int tid  = (int)threadIdx.x;
  const int wv   = tid >> 6;
  const int lane = tid & 63;
  const int lr   = lane & 15;
  const int lg   = lane >> 4;

  __shared__ __align__(16) ushort_t Is[16 * 512];
  __shared__ __align__(16) ushort_t Hs[16 * 512];
  __shared__ float gates[4][16][16];

  short8 wf[32];
#pragma unroll
  for (int i = 0; i < 32; ++i) wf[i] = (short8)((short)(tid * 3 + i));
  ull hv[8];
#pragma unroll
  for (int q = 0; q < 8; ++q) hv[q] = (ull)(tid * 131 + q);
  float c4[4] = {0.f, 0.f, 0.f, 0.f};
  float4 xp0 = {0.1f,0.2f,0.3f,0.4f}, xp1 = xp0, xp2 = xp0, xp3 = xp0;
  const int xr = tid >> 4, xc = (tid & 15) * 16, xsw = (xr & 7) << 3;
  ull accsink = 0;

  for (int k = 0; k < iters; ++k) {
    __syncthreads();                       // B1 (mimics post-poll barrier)
    if (tid < 256) {
      *(short8*)&Is[(xr * 512 + xc) ^ xsw]     = pack8(xp0, xp1);
      *(short8*)&Is[(xr * 512 + xc + 8) ^ xsw] = pack8(xp2, xp3);
      hv[0] += (ull)k;
      ds_stage(Hs, tid, hv);
    }
    __syncthreads();                       // B2 (post-stage)
    if (wv < 4) {
      f32x4 acc0 = {0.f,0.f,0.f,0.f}, acc1 = {0.f,0.f,0.f,0.f};
      const int fb  = lr * 512 + lg * 8;
      const int fsw = (lr & 7) << 3;
#pragma unroll
      for (int kf = 0; kf < 8; ++kf) {
        const short8 af = *(const short8*)&Is[(fb + kf * 32) ^ fsw];
        if (kf & 1) acc1 = __builtin_amdgcn_mfma_f32_16x16x32_bf16(af, wf[kf], acc1, 0, 0, 0);
        else        acc0 = __builtin_amdgcn_mfma_f32_16x16x32_bf16(af, wf[kf], acc0, 0, 0, 0);
      }
#pragma unroll
      for (int kf = 0; kf < 16; ++kf) {
        const short8 af = *(const short8*)&Hs[(fb + kf * 32) ^ fsw];
        if (kf & 1) acc1 = __builtin_amdgcn_mfma_f32_16x16x32_bf16(af, wf[8 + kf], acc1, 0, 0, 0);
        else        acc0 = __builtin_amdgcn_mfma_f32_16x16x32_bf16(af, wf[8 + kf], acc0, 0, 0, 0);
      }
#pragma unroll
      for (int i = 0; i < 4; ++i) {
        float v = acc0[i] + acc1[i] + 0.01f;
        float a = (wv < 3) ? sigm(v) : tanh_fast(v);
        gates[wv][lg * 4 + i][lr] = a;
      }
    }
    __syncthreads();                       // B3 (post-gates)
    if (wv == 0) {
      const int r  = lane >> 2;
      const int cg = lane & 3;
      f32x4 gi = *(const f32x4*)&gates[0][r][cg * 4];
      f32x4 gf = *(const f32x4*)&gates[1][r][cg * 4];
      f32x4 go = *(const f32x4*)&gates[2][r][cg * 4];
      f32x4 gg = *(const f32x4*)&gates[3][r][cg * 4];
      f32x4 nh4;
#pragma unroll
      for (int q = 0; q < 4; ++q) {
        float nc = gf[q] * c4[q] + gi[q] * gg[q];
        float nh = go[q] * tanh_fast(nc);
        nc = fminf(fmaxf(nc, -50.f), 50.f);
        nh = fminf(fmaxf(nh, -50.f), 50.f);
        c4[q] = nc; nh4[q] = nh;
      }
      const ull hvp = pack4bf(nh4);
      *(volatile ull*)(sink + 16 + lane) = hvp;     // local publish (own-XCD L2)
      asm volatile("s_waitcnt vmcnt(0)" ::: "memory");
      if (lane == 0) *(volatile uint32*)flagsink = (uint32)(k + 1);
      accsink += hvp;
    }
  }
  if (tid == 0) sink[0] = accsink;
}

// ============================ LAUNCH ============================
extern "C" void kernel_launch(void* const* d_in, const int* in_sizes, int n_in,
                              void* d_out, int out_size, void* d_ws, size_t ws_size,
                              hipStream_t stream) {
  (void)in_sizes; (void)n_in; (void)out_size;
  const float* x     = (const float*)d_in[0];
  const float* w_ih0 = (const float*)d_in[1];
  const float* w_hh0 = (const float*)d_in[2];
  const float* b0    = (const float*)d_in[3];
  const float* w_ih1 = (const float*)d_in[4];
  const float* w_hh1 = (const float*)d_in[5];
  const float* b1    = (const float*)d_in[6];
  float* out = (float*)d_out;

  char* ws = (char*)d_ws;
  uint32* cnt0F  = (uint32*)(ws + 0);
  uint32* cnt1F  = (uint32*)(ws + 512);
  uint32* consF  = (uint32*)(ws + 1024);
  uint32* h0locF = (uint32*)(ws + 1536);
  uint32* h1locF = (uint32*)(ws + 2048);
  uint32* voteWs = (uint32*)(ws + 2560);
  uint32* probe  = (uint32*)(ws + 3072);
  ushort_t* ring  = (ushort_t*)(ws + 8192);
  ushort_t* h1buf = (ushort_t*)(ws + 8192 + 524288);
  ushort_t* h0loc = (ushort_t*)(ws + 8192 + 524288 + 131072);
  ushort_t* h1loc = (ushort_t*)(ws + 8192 + 524288 + 131072 + 131072);

  hipMemsetAsync(ws, 0, 4096, stream);
  lstm_fused<<<dim3(256), dim3(256), 0, stream>>>(
      x, w_ih0, w_hh0, b0, w_ih1, w_hh1, b1, out,
      cnt0F, cnt1F, consF, h0locF, h1locF, voteWs, probe,
      ring, h1buf, h0loc, h1loc);

  // -------- diagnostic probes (read via rocprof per-dispatch rows) --------
  const size_t PB = (size_t)1 << 20;
  if (ws_size >= PB + 65536) {
    uint32* flagsA = (uint32*)(ws + PB);
    uint32* flagsB = (uint32*)(ws + PB + 256);
    ull*    bufB   = (ull*)(ws + PB + 4096);
    ull*    sinkB  = (ull*)(ws + PB + 20480);
    uint32* flagsC = (uint32*)(ws + PB + 24576);
    ull*    bufC   = (ull*)(ws + PB + 28672);
    ull*    sinkC  = (ull*)(ws + PB + 45056);
    ull*    sinkD  = (ull*)(ws + PB + 49152);
    uint32* flagD  = (uint32*)(ws + PB + 50176);
    hipMemsetAsync(ws + PB, 0, 65536, stream);
    probeA<<<dim3(128), dim3(64),  0, stream>>>(flagsA, 32768, 1500);
    probeB<<<dim3(128), dim3(128), 0, stream>>>(flagsB, bufB, sinkB, 16384, 1500);
    probeC<<<dim3(128), dim3(192), 0, stream>>>(flagsC, bufC, sinkC, 16384, 1500);
    probeD<<<dim3(1),   dim3(448), 0, stream>>>(sinkD, flagD, 32768);
  }
}

// Round 10
// 3689.462 us; speedup vs baseline: 42.9965x; 42.9965x over previous
//
#include <hip/hip_runtime.h>

#define BDIM 64
#define TDIM 1024
#define DDIM 256
#define HDIM 512
#define RING 8

typedef unsigned short ushort_t;
typedef unsigned int uint32;
typedef unsigned long long ull;
typedef __attribute__((ext_vector_type(8))) short short8;
typedef __attribute__((ext_vector_type(4))) float f32x4;

__device__ __forceinline__ ushort_t f2bf(float f) {
  union { float f; uint32 u; } v; v.f = f;
  uint32 u = v.u;
  return (ushort_t)((u + 0x7fffu + ((u >> 16) & 1u)) >> 16);
}

__device__ __forceinline__ short8 pack8(float4 a, float4 b) {
  short8 s;
  s[0] = (short)f2bf(a.x); s[1] = (short)f2bf(a.y);
  s[2] = (short)f2bf(a.z); s[3] = (short)f2bf(a.w);
  s[4] = (short)f2bf(b.x); s[5] = (short)f2bf(b.y);
  s[6] = (short)f2bf(b.z); s[7] = (short)f2bf(b.w);
  return s;
}

__device__ __forceinline__ ull pack4bf(f32x4 v) {
  return (ull)f2bf(v[0]) | ((ull)f2bf(v[1]) << 16)
       | ((ull)f2bf(v[2]) << 32) | ((ull)f2bf(v[3]) << 48);
}

__device__ __forceinline__ float sigm(float x) { return 1.0f / (1.0f + __expf(-x)); }
__device__ __forceinline__ float tanh_fast(float x) { return 1.0f - 2.0f / (__expf(2.0f * x) + 1.0f); }

__device__ __forceinline__ uint32 ld_sc1(uint32* p) {
  return __hip_atomic_load(p, __ATOMIC_RELAXED, __HIP_MEMORY_SCOPE_AGENT);
}
__device__ __forceinline__ void st_sc1(uint32* p, uint32 v) {
  __hip_atomic_store(p, v, __ATOMIC_RELAXED, __HIP_MEMORY_SCOPE_AGENT);
}
__device__ __forceinline__ void st_sc1_u64(ull* p, ull v) {
  __hip_atomic_store(p, v, __ATOMIC_RELAXED, __HIP_MEMORY_SCOPE_AGENT);
}
__device__ __forceinline__ ull ld_sc1_u64(const ull* p) {
  return __hip_atomic_load((ull*)p, __ATOMIC_RELAXED, __HIP_MEMORY_SCOPE_AGENT);
}

__device__ __forceinline__ void wave_poll_sc1(uint32* fl, uint32 tgt) {
  int it = 0;
  for (;;) {
    uint32 v = ld_sc1(fl);
    if (__all((int)(v >= tgt))) break;
    __builtin_amdgcn_s_sleep(1);
    if (++it > 60000) break;   // bounded: wrong beats hang
  }
  asm volatile("" ::: "memory");
}

// ---- fragment-major LDS layout (conflict-free MFMA reads) ----
// 16x512 bf16 tile stored as [kf 0..15][chunk 0..63][8 ushorts],
// chunk(row,lg;kf) = (lg*16+row) ^ (kf&7).
// Read (wave, fragment kf): lane(lr,lg) -> chunk (lg*16+lr)^(kf&7): the 64
// lanes hit 64 distinct consecutive 16B chunks -> all 32 banks uniformly.
__device__ __forceinline__ int frag_off(int row, int kf, int lg) {   // ushort units
  return kf * 512 + (((lg * 16 + row) ^ (kf & 7)) << 3);
}

// stage 2048 ull (16x512 tile, row-major source) into fragment-major LDS.
// thread's ull idx=q*256+tid: row=idx>>7, inner=idx&127 -> k0=inner*4.
__device__ __forceinline__ void ds_stage(ushort_t* dst, int tid, const ull* v) {
#pragma unroll
  for (int q = 0; q < 8; ++q) {
    int idx = q * 256 + tid;
    int row = idx >> 7, inner = idx & 127;
    int kf = inner >> 3, lg = (inner >> 1) & 3, e = (inner & 1) * 4;
    *(ull*)&dst[frag_off(row, kf, lg) + e] = v[q];
  }
}

__device__ __forceinline__ void load_sc1_8(const ull* src, int tid, ull* v) {
#pragma unroll
  for (int q = 0; q < 8; ++q) v[q] = ld_sc1_u64(src + q * 256 + tid);
}

__global__ void __launch_bounds__(256, 1)
lstm_fused(const float* __restrict__ x,
           const float* __restrict__ w_ih0, const float* __restrict__ w_hh0,
           const float* __restrict__ b0,
           const float* __restrict__ w_ih1, const float* __restrict__ w_hh1,
           const float* __restrict__ b1,
           float* __restrict__ out,
           uint32* cnt0F, uint32* cnt1F, uint32* consF,
           ushort_t* ring, ushort_t* h1buf)
{
  const int b     = (int)blockIdx.x;
  const int g     = b & 7;
  const int layer = g >> 2;
  const int bt    = g & 3;
  const int ct    = b >> 3;
  const int tid   = (int)threadIdx.x;
  const int wv    = tid >> 6;
  const int lane  = tid & 63;
  const int lr    = lane & 15;
  const int lg    = lane >> 4;

  __shared__ __align__(16) ushort_t Is[16 * 512];   // fragment-major
  __shared__ __align__(16) ushort_t Hs[16 * 512];   // fragment-major
  __shared__ float gates[4][16][16];

  const int NI  = layer ? 16 : 8;
  const int Din = layer ? HDIM : DDIM;
  const float* wih = layer ? w_ih1 : w_ih0;
  const float* whh = layer ? w_hh1 : w_hh0;
  const float* bb  = layer ? b1 : b0;
  const int grow = wv * HDIM + ct * 16 + lr;

  short8 wf[32];
#pragma unroll
  for (int kf = 0; kf < 32; ++kf) wf[kf] = (short8)((short)0);
#pragma unroll
  for (int kf = 0; kf < 32; ++kf) {
    if (kf < NI + 16) {
      const float* src;
      if (kf < NI) src = wih + (size_t)grow * Din + (size_t)kf * 32 + lg * 8;
      else         src = whh + (size_t)grow * HDIM + (size_t)(kf - NI) * 32 + lg * 8;
      float4 a = *(const float4*)(src);
      float4 bq = *(const float4*)(src + 4);
      wf[kf] = pack8(a, bq);
    }
  }
  const float bias = bb[grow];

  const ull* ring_u  = (const ull*)ring;
  const ull* h1buf_u = (const ull*)h1buf;

  float c4[4] = {0.f, 0.f, 0.f, 0.f};     // wave0: 4 cell states
  float4 xp0, xp1, xp2, xp3;
  // x staging map: thread -> row xr, col block (tid&15)*16 (two 16B chunks)
  const int xr = tid >> 4;
  const int xcb = tid & 15;

  if (layer == 0) {
    const float4* xv = (const float4*)(x + (size_t)(bt * 16 + xr) * (TDIM * DDIM) + xcb * 16);
    xp0 = xv[0]; xp1 = xv[1]; xp2 = xv[2]; xp3 = xv[3];
  }

  for (int t = 0; t < TDIM; ++t) {
    // ---- P1: polls ----
    if (layer == 0) {
      if (wv == 0) {
        if (t > 0) wave_poll_sc1(cnt0F + bt * 32 + (lane & 31), (uint32)t);
      } else if (wv == 1) {
        if (t >= RING) wave_poll_sc1(consF + bt * 32 + (lane & 31), (uint32)(t - RING + 1));
      }
    } else {
      if (wv == 0) {
        if (t > 0) wave_poll_sc1(cnt1F + bt * 32 + (lane & 31), (uint32)t);
      } else if (wv == 1) {
        wave_poll_sc1(cnt0F + bt * 32 + (lane & 31), (uint32)(t + 1));   // y0[t] ready
      }
    }
    __syncthreads();

    // ---- P2/P3: stage inputs ----
    if (layer == 0) {
      {  // x[t] from prefetch regs -> fragment-major chunks (cols xcb*16, +8)
        const int c0 = xcb * 16;
        *(short8*)&Is[frag_off(xr, c0 >> 5, (c0 >> 3) & 3)] = pack8(xp0, xp1);
        const int c1 = c0 + 8;
        *(short8*)&Is[frag_off(xr, c1 >> 5, (c1 >> 3) & 3)] = pack8(xp2, xp3);
      }
      if (t > 0) {
        ull hv[8];
        load_sc1_8(ring_u + (size_t)((t - 1) & (RING - 1)) * 8192 + (size_t)bt * 2048, tid, hv);
        ds_stage(Hs, tid, hv);
      }
    } else {
      ull rv[8], hv[8];
      load_sc1_8(ring_u + (size_t)(t & (RING - 1)) * 8192 + (size_t)bt * 2048, tid, rv);
      if (t > 0)
        load_sc1_8(h1buf_u + (size_t)((t - 1) & 1) * 8192 + (size_t)bt * 2048, tid, hv);
      ds_stage(Is, tid, rv);
      if (t > 0) ds_stage(Hs, tid, hv);
    }
    __syncthreads();
    if (layer == 1 && tid == 0)
      st_sc1(consF + bt * 32 + ct, (uint32)(t + 1));   // ring slot consumed

    // ---- P5: MFMA (conflict-free fragment reads) ----
    f32x4 acc0 = {0.f, 0.f, 0.f, 0.f}, acc1 = {0.f, 0.f, 0.f, 0.f};
#pragma unroll
    for (int kf = 0; kf < 16; ++kf) {
      if (kf < NI) {
        const short8 af = *(const short8*)&Is[frag_off(lr, kf, lg)];
        if (kf & 1) acc1 = __builtin_amdgcn_mfma_f32_16x16x32_bf16(af, wf[kf], acc1, 0, 0, 0);
        else        acc0 = __builtin_amdgcn_mfma_f32_16x16x32_bf16(af, wf[kf], acc0, 0, 0, 0);
      }
    }
    if (t > 0) {
#pragma unroll
      for (int kf = 0; kf < 16; ++kf) {
        const short8 af = *(const short8*)&Hs[frag_off(lr, kf, lg)];
        if (kf & 1) acc1 = __builtin_amdgcn_mfma_f32_16x16x32_bf16(af, wf[NI + kf], acc1, 0, 0, 0);
        else        acc0 = __builtin_amdgcn_mfma_f32_16x16x32_bf16(af, wf[NI + kf], acc0, 0, 0, 0);
      }
    }
#pragma unroll
    for (int i = 0; i < 4; ++i) {
      float v = acc0[i] + acc1[i] + bias;
      float a = (wv < 3) ? sigm(v) : tanh_fast(v);
      gates[wv][lg * 4 + i][lr] = a;
    }
    __syncthreads();

    // ---- P6/P7: pointwise (wave0) + publish; others prefetch x ----
    if (layer == 0 && wv != 0 && t + 1 < TDIM) {
      const float4* xv = (const float4*)(x + (size_t)(bt * 16 + xr) * (TDIM * DDIM)
                                           + (size_t)(t + 1) * DDIM + xcb * 16);
      xp0 = xv[0]; xp1 = xv[1]; xp2 = xv[2]; xp3 = xv[3];
    }
    if (wv == 0) {
      const int r  = lane >> 2;
      const int cg = lane & 3;
      f32x4 gi = *(const f32x4*)&gates[0][r][cg * 4];
      f32x4 gf = *(const f32x4*)&gates[1][r][cg * 4];
      f32x4 go = *(const f32x4*)&gates[2][r][cg * 4];
      f32x4 gg = *(const f32x4*)&gates[3][r][cg * 4];
      f32x4 nh4, nc4;
#pragma unroll
      for (int k = 0; k < 4; ++k) {
        float nc = gf[k] * c4[k] + gi[k] * gg[k];
        float nh = go[k] * tanh_fast(nc);     // h uses UNCLIPPED c
        nc = fminf(fmaxf(nc, -50.f), 50.f);
        nh = fminf(fmaxf(nh, -50.f), 50.f);
        c4[k] = nc; nh4[k] = nh; nc4[k] = nc;
      }
      const ull hv = pack4bf(nh4);
      ull* dst;
      if (layer == 0)
        dst = (ull*)(ring_u + (size_t)(t & (RING - 1)) * 8192
                     + (size_t)(bt * 16 + r) * 128 + ct * 4 + cg);
      else
        dst = (ull*)(h1buf_u + (size_t)(t & 1) * 8192
                     + (size_t)(bt * 16 + r) * 128 + ct * 4 + cg);
      st_sc1_u64(dst, hv);
      asm volatile("s_waitcnt vmcnt(0)" ::: "memory");
      if (lane == 0) st_sc1((layer == 0 ? cnt0F : cnt1F) + bt * 32 + ct, (uint32)(t + 1));
      if (layer == 1)
        *(f32x4*)&out[(size_t)(bt * 16 + r) * (TDIM * HDIM) + (size_t)t * HDIM + ct * 16 + cg * 4] = nh4;
      if (t == TDIM - 1) {
        const size_t OH = (size_t)BDIM * TDIM * HDIM;
        const size_t OC = OH + 2 * (size_t)BDIM * HDIM;
        *(f32x4*)&out[OH + (size_t)layer * BDIM * HDIM + (size_t)(bt * 16 + r) * HDIM + ct * 16 + cg * 4] = nh4;
        *(f32x4*)&out[OC + (size_t)layer * BDIM * HDIM + (size_t)(bt * 16 + r) * HDIM + ct * 16 + cg * 4] = nc4;
      }
      if (layer == 0 && t + 1 < TDIM) {
        const float4* xv = (const float4*)(x + (size_t)(bt * 16 + xr) * (TDIM * DDIM)
                                             + (size_t)(t + 1) * DDIM + xcb * 16);
        xp0 = xv[0]; xp1 = xv[1]; xp2 = xv[2]; xp3 = xv[3];
      }
    }
  }
}

extern "C" void kernel_launch(void* const* d_in, const int* in_sizes, int n_in,
                              void* d_out, int out_size, void* d_ws, size_t ws_size,
                              hipStream_t stream) {
  (void)in_sizes; (void)n_in; (void)out_size; (void)ws_size;
  const float* x     = (const float*)d_in[0];
  const float* w_ih0 = (const float*)d_in[1];
  const float* w_hh0 = (const float*)d_in[2];
  const float* b0    = (const float*)d_in[3];
  const float* w_ih1 = (const float*)d_in[4];
  const float* w_hh1 = (const float*)d_in[5];
  const float* b1    = (const float*)d_in[6];
  float* out = (float*)d_out;

  char* ws = (char*)d_ws;
  uint32* cnt0F = (uint32*)(ws + 0);       // [4][32]
  uint32* cnt1F = (uint32*)(ws + 512);     // [4][32]
  uint32* consF = (uint32*)(ws + 1024);    // [4][32]
  ushort_t* ring  = (ushort_t*)(ws + 8192);                 // [8][64][512] bf16 (512KB)
  ushort_t* h1buf = (ushort_t*)(ws + 8192 + 524288);        // [2][64][512] bf16 (128KB)

  hipMemsetAsync(ws, 0, 4096, stream);
  lstm_fused<<<dim3(256), dim3(256), 0, stream>>>(
      x, w_ih0, w_hh0, b0, w_ih1, w_hh1, b1, out,
      cnt0F, cnt1F, consF, ring, h1buf);
}